// Round 8
// baseline (1487.613 us; speedup 1.0000x reference)
//
#include <hip/hip_runtime.h>
#include <math.h>

#define TOK   1024
#define HSZ   1024
#define DIM   128
#define NWRDC 32000
#define NTGTC 2000

typedef __attribute__((ext_vector_type(8))) short bf16x8;
typedef __attribute__((ext_vector_type(4))) float f32x4;

__device__ __forceinline__ ushort f2bf(float x) {
    union { float f; uint u; } c; c.f = x;
    return (ushort)((c.u + 0x7fffu + ((c.u >> 16) & 1u)) >> 16);
}
__device__ __forceinline__ float bf2f(ushort h) {
    union { uint u; float f; } c; c.u = ((uint)h) << 16;
    return c.f;
}
__device__ __forceinline__ uint4 pk8(const ushort v[8]) {
    uint4 u;
    u.x = (uint)v[0] | ((uint)v[1] << 16);
    u.y = (uint)v[2] | ((uint)v[3] << 16);
    u.z = (uint)v[4] | ((uint)v[5] << 16);
    u.w = (uint)v[6] | ((uint)v[7] << 16);
    return u;
}
// sorted top-3 insert, ties -> smaller index wins
__device__ __forceinline__ void ins3(float v, int ix, float s[3], int ii[3]) {
    if (v > s[0] || (v == s[0] && ix < ii[0])) {
        s[2] = s[1]; ii[2] = ii[1]; s[1] = s[0]; ii[1] = ii[0]; s[0] = v; ii[0] = ix;
    } else if (v > s[1] || (v == s[1] && ix < ii[1])) {
        s[2] = s[1]; ii[2] = ii[1]; s[1] = v; ii[1] = ix;
    } else if (v > s[2] || (v == s[2] && ix < ii[2])) {
        s[2] = v; ii[2] = ix;
    }
}

#define GLL16(SRC, DST) __builtin_amdgcn_global_load_lds( \
    (const __attribute__((address_space(1))) void*)(SRC), \
    (__attribute__((address_space(3))) void*)(DST), 16, 0, 0)

// ---------------------------------------------------------------------------
// split ctx into 3 bf16 terms (heads use hi; cpy uses all 3)
// ---------------------------------------------------------------------------
__global__ __launch_bounds__(256) void split_ctx3(
    const float* __restrict__ x, ushort* __restrict__ hp,
    ushort* __restrict__ mp, ushort* __restrict__ lp)
{
    const int i4 = (blockIdx.x * 256 + threadIdx.x) * 4;
    float4 v = *(const float4*)(x + i4);
    float xs[4] = {v.x, v.y, v.z, v.w};
    ushort hh[4], mm[4], ll[4];
    #pragma unroll
    for (int k = 0; k < 4; ++k) {
        ushort h = f2bf(xs[k]);
        float r1 = xs[k] - bf2f(h);
        ushort m = f2bf(r1);
        ushort l = f2bf(r1 - bf2f(m));
        hh[k] = h; mm[k] = m; ll[k] = l;
    }
    uint2 u;
    u.x = (uint)hh[0] | ((uint)hh[1] << 16); u.y = (uint)hh[2] | ((uint)hh[3] << 16);
    *(uint2*)(hp + i4) = u;
    u.x = (uint)mm[0] | ((uint)mm[1] << 16); u.y = (uint)mm[2] | ((uint)mm[3] << 16);
    *(uint2*)(mp + i4) = u;
    u.x = (uint)ll[0] | ((uint)ll[1] << 16); u.y = (uint)ll[2] | ((uint)ll[3] << 16);
    *(uint2*)(lp + i4) = u;
}

// ---------------------------------------------------------------------------
// conv_wt: W [1024][V] f32 -> transposed Wh [Vpad][1024] bf16 (RNE).
// grid (Vpad/256, 8); blockIdx.y covers 128 k-rows. Pad cols >= V zeroed.
// ---------------------------------------------------------------------------
__global__ __launch_bounds__(256) void conv_wt(
    const float* __restrict__ W, int V, ushort* __restrict__ Wh)
{
    const int col = blockIdx.x * 256 + threadIdx.x;
    const int k0 = blockIdx.y * 128;
    for (int kk = 0; kk < 128; kk += 8) {
        ushort h8[8];
        #pragma unroll
        for (int q = 0; q < 8; ++q) {
            float x = (col < V) ? W[(size_t)(k0 + kk + q) * V + col] : 0.f;
            h8[q] = f2bf(x);
        }
        *(uint4*)(Wh + (size_t)col * 1024 + k0 + kk) = pk8(h8);
    }
}

// ---------------------------------------------------------------------------
// cpy_fused (r5-proven body, standalone): C-tile = ctx @ W_cpy (3-term split,
// 6 passes) with fused partial pcpy dot -> pcpyP[colsplit][t]. 64 blocks.
// ---------------------------------------------------------------------------
__global__ __launch_bounds__(256, 2) void cpy_fused(
    const ushort* __restrict__ ahi, const ushort* __restrict__ amd,
    const ushort* __restrict__ alo, const float* __restrict__ Wc,
    const float* __restrict__ ctx, const float* __restrict__ bc,
    float* __restrict__ pcpyP)
{
    __shared__ __align__(16) ushort sm[30720];
    ushort* Ah = sm;
    ushort* Am = sm + 5120;
    ushort* Al = sm + 10240;
    ushort* Bh = sm + 15360;
    ushort* Bm = sm + 20480;
    ushort* Bl = sm + 25600;

    const int tid  = threadIdx.x;
    const int lane = tid & 63;
    const int fr   = lane & 15;
    const int fg   = lane >> 4;
    const int w    = tid >> 6;
    const int wrow = w >> 1;
    const int wcol = w & 1;
    const int cb   = (int)blockIdx.x;
    const int t0   = (cb >> 3) * 128;
    const int c0   = (cb & 7) * 128;

    const int arow = tid >> 2, akc = tid & 3;
    const int bcol = tid & 127, bkc0 = tid >> 7;

    f32x4 zero4 = {0.f, 0.f, 0.f, 0.f};
    f32x4 acc[4][4];
    #pragma unroll
    for (int i = 0; i < 4; ++i)
        #pragma unroll
        for (int j = 0; j < 4; ++j) acc[i][j] = zero4;

    for (int h0 = 0; h0 < HSZ; h0 += 32) {
        uint4 aH[2], aM[2], aL[2];
        float bx[2][8];
        #pragma unroll
        for (int rr = 0; rr < 2; ++rr) {
            const size_t so = (size_t)(t0 + arow + rr * 64) * HSZ + h0 + akc * 8;
            aH[rr] = *(const uint4*)(ahi + so);
            aM[rr] = *(const uint4*)(amd + so);
            aL[rr] = *(const uint4*)(alo + so);
        }
        #pragma unroll
        for (int rr = 0; rr < 2; ++rr) {
            const int kc = bkc0 + rr * 2;
            const float* wp = Wc + (size_t)(h0 + kc * 8) * HSZ + c0 + bcol;
            #pragma unroll
            for (int j = 0; j < 8; ++j) bx[rr][j] = wp[(size_t)j * HSZ];
        }
        __syncthreads();
        #pragma unroll
        for (int rr = 0; rr < 2; ++rr) {
            const int row = arow + rr * 64;
            *(uint4*)(Ah + row * 40 + akc * 8) = aH[rr];
            *(uint4*)(Am + row * 40 + akc * 8) = aM[rr];
            *(uint4*)(Al + row * 40 + akc * 8) = aL[rr];
        }
        #pragma unroll
        for (int rr = 0; rr < 2; ++rr) {
            const int kc = bkc0 + rr * 2;
            ushort hh[8], mm[8], ll[8];
            #pragma unroll
            for (int j = 0; j < 8; ++j) {
                float x = bx[rr][j];
                ushort h = f2bf(x);
                float r1 = x - bf2f(h);
                ushort m = f2bf(r1);
                hh[j] = h; mm[j] = m; ll[j] = f2bf(r1 - bf2f(m));
            }
            *(uint4*)(Bh + bcol * 40 + kc * 8) = pk8(hh);
            *(uint4*)(Bm + bcol * 40 + kc * 8) = pk8(mm);
            *(uint4*)(Bl + bcol * 40 + kc * 8) = pk8(ll);
        }
        __syncthreads();
        bf16x8 a1[4], a2[4], a3[4];
        #pragma unroll
        for (int i = 0; i < 4; ++i) {
            const int row = wrow * 64 + i * 16 + fr;
            a1[i] = *(const bf16x8*)(Ah + row * 40 + fg * 8);
            a2[i] = *(const bf16x8*)(Am + row * 40 + fg * 8);
            a3[i] = *(const bf16x8*)(Al + row * 40 + fg * 8);
        }
        #pragma unroll
        for (int j = 0; j < 4; ++j) {
            const int cr = wcol * 64 + j * 16 + fr;
            bf16x8 b1 = *(const bf16x8*)(Bh + cr * 40 + fg * 8);
            bf16x8 b2 = *(const bf16x8*)(Bm + cr * 40 + fg * 8);
            bf16x8 b3 = *(const bf16x8*)(Bl + cr * 40 + fg * 8);
            #pragma unroll
            for (int i = 0; i < 4; ++i) {
                acc[i][j] = __builtin_amdgcn_mfma_f32_16x16x32_bf16(a1[i], b1, acc[i][j], 0, 0, 0);
                acc[i][j] = __builtin_amdgcn_mfma_f32_16x16x32_bf16(a1[i], b2, acc[i][j], 0, 0, 0);
                acc[i][j] = __builtin_amdgcn_mfma_f32_16x16x32_bf16(a2[i], b1, acc[i][j], 0, 0, 0);
                acc[i][j] = __builtin_amdgcn_mfma_f32_16x16x32_bf16(a1[i], b3, acc[i][j], 0, 0, 0);
                acc[i][j] = __builtin_amdgcn_mfma_f32_16x16x32_bf16(a3[i], b1, acc[i][j], 0, 0, 0);
                acc[i][j] = __builtin_amdgcn_mfma_f32_16x16x32_bf16(a2[i], b2, acc[i][j], 0, 0, 0);
            }
        }
    }

    __syncthreads();
    float* red = (float*)sm;
    float bb[4];
    #pragma unroll
    for (int j = 0; j < 4; ++j) bb[j] = bc[c0 + wcol * 64 + j * 16 + fr];
    #pragma unroll
    for (int i = 0; i < 4; ++i) {
        #pragma unroll
        for (int r = 0; r < 4; ++r) {
            const int trow = wrow * 64 + i * 16 + fg * 4 + r;
            const float* cx = ctx + (size_t)(t0 + trow) * HSZ + c0;
            float s = 0.f;
            #pragma unroll
            for (int j = 0; j < 4; ++j) {
                const int dd = wcol * 64 + j * 16 + fr;
                s += (acc[i][j][r] + bb[j]) * cx[dd];
            }
            #pragma unroll
            for (int off = 1; off < 16; off <<= 1) s += __shfl_xor(s, off, 64);
            if (fr == 0) red[trow * 2 + wcol] = s;
        }
    }
    __syncthreads();
    if (tid < 128)
        pcpyP[(size_t)(cb & 7) * TOK + t0 + tid] = red[tid * 2] + red[tid * 2 + 1];
}

// ---------------------------------------------------------------------------
// head_pre (r6-proven, VERBATIM): single-pass bf16 logits GEMM, A and B both
// via global_load_lds (double-buffered, swizzled layout), + exp/sum/top-3 +
// P@emb. Grid (NVx, 8): blockIdx.x=split, blockIdx.y=token block.
// ---------------------------------------------------------------------------
__global__ __launch_bounds__(256, 2) void head_pre(
    const ushort* __restrict__ ctx_hi, const ushort* __restrict__ Wt,
    const float* __restrict__ bias, const float* __restrict__ g,
    const float* __restrict__ emb,
    int V, int ldg, int tps, int n_tiles,
    float* __restrict__ wsW, float* __restrict__ wsBV,
    int* __restrict__ wsBI, float* __restrict__ wsE)
{
    __shared__ __align__(16) char smem[60416];
    ushort* Pl = (ushort*)smem;
    ushort* EM = (ushort*)(smem + 34816);
    float* sm_wsum = (float*)(smem + 53248);
    float* sm_bval = (float*)(smem + 54272);
    int*   sm_bidx = (int*)(smem + 57344);

    const int tid  = threadIdx.x;
    const int lane = tid & 63;
    const int fr   = lane & 15;
    const int fg   = lane >> 4;
    const int wv   = tid >> 6;
    const int wrow = wv >> 1;
    const int wcol = wv & 1;
    const int split = (int)blockIdx.x;
    const int t0    = (int)blockIdx.y * 128;

    if (tid < 128) {
        sm_wsum[tid * 2] = 0.f; sm_wsum[tid * 2 + 1] = 0.f;
        #pragma unroll
        for (int s = 0; s < 3; ++s) {
            sm_bval[(tid * 2) * 3 + s] = -INFINITY;
            sm_bval[(tid * 2 + 1) * 3 + s] = -INFINITY;
            sm_bidx[(tid * 2) * 3 + s] = 0;
            sm_bidx[(tid * 2 + 1) * 3 + s] = 0;
        }
    }

    // fragment read offsets
    const int chunkRd0 = (((fr & 1) << 2) | fg) ^ ((fr >> 1) & 7);
    int aRd[4], bRd[4];
    #pragma unroll
    for (int i = 0; i < 4; ++i) {
        aRd[i] = wrow * 4096 + i * 1024 + (fr >> 1) * 128 + ((chunkRd0 ^ i) << 4);
        bRd[i] = wcol * 4096 + i * 1024 + (fr >> 1) * 128 + ((chunkRd0 ^ i) << 4);
    }

    // gll lane constants (pre-XOR'd source -> linear dest reproduces layout)
    const int v_ = (lane & 7) ^ (lane >> 3) ^ (wv & 3);
    int rowq[2];
    #pragma unroll
    for (int q = 0; q < 2; ++q)
        rowq[q] = 2 * (q * 32 + wv * 8 + (lane >> 3)) + (v_ >> 2);
    const int glK = (v_ & 3) * 8;
    const size_t srcA0 = (size_t)(t0 + rowq[0]) * HSZ + glK;
    const size_t srcA1 = (size_t)(t0 + rowq[1]) * HSZ + glK;
    const int dA0 = wv * 1024, dA1 = 4096 + wv * 1024;

    f32x4 zero4 = {0.f, 0.f, 0.f, 0.f};
    f32x4 Eacc[4][4];
    #pragma unroll
    for (int i = 0; i < 4; ++i)
        #pragma unroll
        for (int j = 0; j < 4; ++j) Eacc[i][j] = zero4;

    int tbeg = split * tps;
    int tend = tbeg + tps; if (tend > n_tiles) tend = n_tiles;

    for (int tt = tbeg; tt < tend; ++tt) {
        const int c0 = tt * 128;
        const size_t srcB0 = (size_t)(c0 + rowq[0]) * HSZ + glK;
        const size_t srcB1 = (size_t)(c0 + rowq[1]) * HSZ + glK;
        f32x4 acc[4][4];
        #pragma unroll
        for (int i = 0; i < 4; ++i)
            #pragma unroll
            for (int j = 0; j < 4; ++j) acc[i][j] = zero4;

        GLL16(ctx_hi + srcA0, smem + dA0);
        GLL16(ctx_hi + srcA1, smem + dA1);
        GLL16(Wt + srcB0, smem + 16384 + dA0);
        GLL16(Wt + srcB1, smem + 16384 + dA1);
        __syncthreads();

        for (int ks = 0; ks < 32; ++ks) {
            const int cur = ks & 1;
            if (ks < 31) {
                const int so = (ks + 1) * 32;
                char* an = smem + (cur ^ 1) * 8192;
                char* bn = smem + 16384 + (cur ^ 1) * 8192;
                GLL16(ctx_hi + srcA0 + so, an + dA0);
                GLL16(ctx_hi + srcA1 + so, an + dA1);
                GLL16(Wt + srcB0 + so, bn + dA0);
                GLL16(Wt + srcB1 + so, bn + dA1);
            }
            char* bA = smem + cur * 8192;
            char* bB = smem + 16384 + cur * 8192;
            bf16x8 ah[4], bh[4];
            #pragma unroll
            for (int i = 0; i < 4; ++i) ah[i] = *(const bf16x8*)(bA + aRd[i]);
            #pragma unroll
            for (int j = 0; j < 4; ++j) bh[j] = *(const bf16x8*)(bB + bRd[j]);
            #pragma unroll
            for (int j = 0; j < 4; ++j)
                #pragma unroll
                for (int i = 0; i < 4; ++i)
                    acc[i][j] = __builtin_amdgcn_mfma_f32_16x16x32_bf16(ah[i], bh[j], acc[i][j], 0, 0, 0);
            __syncthreads();
        }

        // ---- epilogue: bias + gumbel + exp, P -> LDS, Z + top-3 stats ----
        float bias4[4];
        #pragma unroll
        for (int j = 0; j < 4; ++j) {
            const int gc = c0 + wcol * 64 + j * 16 + fr;
            bias4[j] = (gc < V) ? bias[gc] : 0.f;
        }
        #pragma unroll
        for (int i = 0; i < 4; ++i) {
            #pragma unroll
            for (int r = 0; r < 4; ++r) {
                const int trow = wrow * 64 + i * 16 + fg * 4 + r;
                const float* gp = g + (size_t)(t0 + trow) * ldg + c0 + wcol * 64 + fr;
                float esum = 0.f;
                float t3v[3] = {-INFINITY, -INFINITY, -INFINITY};
                int   t3i[3] = {0, 0, 0};
                #pragma unroll
                for (int j = 0; j < 4; ++j) {
                    const int gc = c0 + wcol * 64 + j * 16 + fr;
                    float e = 0.f;
                    if (gc < V) {
                        const float s = acc[i][j][r] + bias4[j] + gp[j * 16];
                        e = __expf(s);
                        esum += e;
                        ins3(s, gc, t3v, t3i);
                    }
                    Pl[trow * 136 + wcol * 64 + j * 16 + fr] = f2bf(e);
                }
                #pragma unroll
                for (int off = 1; off < 16; off <<= 1) {
                    float o0 = __shfl_xor(t3v[0], off, 64);
                    float o1 = __shfl_xor(t3v[1], off, 64);
                    float o2 = __shfl_xor(t3v[2], off, 64);
                    int q0 = __shfl_xor(t3i[0], off, 64);
                    int q1 = __shfl_xor(t3i[1], off, 64);
                    int q2 = __shfl_xor(t3i[2], off, 64);
                    esum += __shfl_xor(esum, off, 64);
                    ins3(o0, q0, t3v, t3i);
                    ins3(o1, q1, t3v, t3i);
                    ins3(o2, q2, t3v, t3i);
                }
                if (fr == 0) {
                    const int sb = (trow * 2 + wcol) * 3;
                    sm_wsum[trow * 2 + wcol] += esum;
                    float sh[3] = {sm_bval[sb], sm_bval[sb + 1], sm_bval[sb + 2]};
                    int shi[3] = {sm_bidx[sb], sm_bidx[sb + 1], sm_bidx[sb + 2]};
                    ins3(t3v[0], t3i[0], sh, shi);
                    ins3(t3v[1], t3i[1], sh, shi);
                    ins3(t3v[2], t3i[2], sh, shi);
                    sm_bval[sb] = sh[0]; sm_bval[sb + 1] = sh[1]; sm_bval[sb + 2] = sh[2];
                    sm_bidx[sb] = shi[0]; sm_bidx[sb + 1] = shi[1]; sm_bidx[sb + 2] = shi[2];
                }
            }
        }

        // ---- E-GEMM in two 64-col halves ----
        #pragma unroll
        for (int hf = 0; hf < 2; ++hf) {
            __syncthreads();
            #pragma unroll
            for (int rr = 0; rr < 4; ++rr) {
                const int task = tid + rr * 256;
                const int dd0 = task & 127;
                const int cc = task >> 7;
                ushort o8[8];
                #pragma unroll
                for (int j = 0; j < 8; ++j) {
                    const int gc = c0 + hf * 64 + cc * 8 + j;
                    o8[j] = (gc < V) ? f2bf(emb[(size_t)gc * DIM + dd0]) : (ushort)0;
                }
                *(uint4*)(EM + dd0 * 72 + cc * 8) = pk8(o8);
            }
            __syncthreads();
            #pragma unroll
            for (int ksb = 0; ksb < 2; ++ksb) {
                bf16x8 ap[4];
                #pragma unroll
                for (int i = 0; i < 4; ++i) {
                    const int row = wrow * 64 + i * 16 + fr;
                    ap[i] = *(const bf16x8*)(Pl + row * 136 + hf * 64 + ksb * 32 + fg * 8);
                }
                #pragma unroll
                for (int j = 0; j < 4; ++j) {
                    const int dd = wcol * 64 + j * 16 + fr;
                    bf16x8 eb = *(const bf16x8*)(EM + dd * 72 + ksb * 32 + fg * 8);
                    #pragma unroll
                    for (int i = 0; i < 4; ++i)
                        Eacc[i][j] = __builtin_amdgcn_mfma_f32_16x16x32_bf16(ap[i], eb, Eacc[i][j], 0, 0, 0);
                }
            }
        }
        __syncthreads();
    }

    __syncthreads();
    if (tid < 128) {
        const int sb0 = (tid * 2) * 3, sb1 = (tid * 2 + 1) * 3;
        float v3[3] = {sm_bval[sb0], sm_bval[sb0 + 1], sm_bval[sb0 + 2]};
        int i3[3] = {sm_bidx[sb0], sm_bidx[sb0 + 1], sm_bidx[sb0 + 2]};
        ins3(sm_bval[sb1], sm_bidx[sb1], v3, i3);
        ins3(sm_bval[sb1 + 1], sm_bidx[sb1 + 1], v3, i3);
        ins3(sm_bval[sb1 + 2], sm_bidx[sb1 + 2], v3, i3);
        const size_t o = (size_t)split * TOK + t0 + tid;
        wsW[o] = sm_wsum[tid * 2] + sm_wsum[tid * 2 + 1];
        #pragma unroll
        for (int s = 0; s < 3; ++s) { wsBV[o * 3 + s] = v3[s]; wsBI[o * 3 + s] = i3[s]; }
    }
    #pragma unroll
    for (int i = 0; i < 4; ++i)
        #pragma unroll
        for (int j = 0; j < 4; ++j)
            #pragma unroll
            for (int r = 0; r < 4; ++r) {
                const int trow = wrow * 64 + i * 16 + fg * 4 + r;
                const int dd   = wcol * 64 + j * 16 + fr;
                wsE[((size_t)split * TOK + t0 + trow) * DIM + dd] = Eacc[i][j][r];
            }
}

// ---------------------------------------------------------------------------
// combine2 (r7-proven): merge partials; conditional exact (f64) recompute of
// top-3 candidates from the ORIGINAL W when the approx gap <= EPS.
// ---------------------------------------------------------------------------
__global__ __launch_bounds__(128) void combine2(
    const int* __restrict__ inp_word, const float* __restrict__ masks,
    const int* __restrict__ spt_mask, const int* __restrict__ tgt_ids,
    const float* __restrict__ word_emb, const float* __restrict__ pcpyP,
    const float* __restrict__ g_nrm, const float* __restrict__ g_spt,
    const float* __restrict__ ctx,
    const float* __restrict__ b_nrm, const float* __restrict__ b_spt,
    const float* __restrict__ W_nrm, const float* __restrict__ W_spt,
    const float* __restrict__ nW, const float* __restrict__ nBV,
    const int* __restrict__ nBI, const float* __restrict__ nE, int NVn,
    const float* __restrict__ sW, const float* __restrict__ sBV,
    const int* __restrict__ sBI, const float* __restrict__ sE, int NVs,
    float* __restrict__ out)
{
    __shared__ double sredN[2][3];
    __shared__ double sredS[2][3];
    const int t = (int)blockIdx.x;
    const int d = (int)threadIdx.x;

    float Wn = 0.f, En = 0.f;
    float cv[3] = {-INFINITY, -INFINITY, -INFINITY}; int ci[3] = {0, 0, 0};
    for (int v = 0; v < NVn; ++v) {
        const size_t o = (size_t)v * TOK + t;
        Wn += nW[o];
        En += nE[o * DIM + d];
        #pragma unroll
        for (int s = 0; s < 3; ++s) ins3(nBV[o * 3 + s], nBI[o * 3 + s], cv, ci);
    }
    float Ws = 0.f, Es = 0.f;
    float dv[3] = {-INFINITY, -INFINITY, -INFINITY}; int di[3] = {0, 0, 0};
    for (int v = 0; v < NVs; ++v) {
        const size_t o = (size_t)v * TOK + t;
        Ws += sW[o];
        Es += sE[o * DIM + d];
        #pragma unroll
        for (int s = 0; s < 3; ++s) ins3(sBV[o * 3 + s], sBI[o * 3 + s], dv, di);
    }

    float pc = 0.f;
    #pragma unroll
    for (int y = 0; y < 8; ++y) pc += pcpyP[(size_t)y * TOK + t];
    const int iw = inp_word[t];
    const float sc = pc + g_nrm[(size_t)t * (NWRDC + 1) + NWRDC];

    const float EPS = 0.02f;
    const bool needN = (cv[0] - cv[1] <= EPS) || (fabsf(sc - cv[0]) <= EPS);
    const bool needS = (dv[0] - dv[1] <= EPS);

    if (needN || needS) {
        float cxv[8];
        #pragma unroll
        for (int q = 0; q < 8; ++q) cxv[q] = ctx[(size_t)t * HSZ + d * 8 + q];
        #pragma unroll
        for (int c = 0; c < 3; ++c) {
            double p = 0.0;
            if (needN && cv[c] > -1e30f) {
                const float* wc = W_nrm + ci[c];
                #pragma unroll
                for (int q = 0; q < 8; ++q)
                    p += (double)cxv[q] * (double)wc[(size_t)(d * 8 + q) * NWRDC];
            }
            #pragma unroll
            for (int off = 32; off > 0; off >>= 1) p += __shfl_down(p, off, 64);
            if ((d & 63) == 0) sredN[d >> 6][c] = p;
        }
        #pragma unroll
        for (int c = 0; c < 3; ++c) {
            double p = 0.0;
            if (needS && dv[c] > -1e30f) {
                const float* wc = W_spt + di[c];
                #pragma unroll
                for (int q = 0; q < 8; ++q)
                    p += (double)cxv[q] * (double)wc[(size_t)(d * 8 + q) * NTGTC];
            }
            #pragma unroll
            for (int off = 32; off > 0; off >>= 1) p += __shfl_down(p, off, 64);
            if ((d & 63) == 0) sredS[d >> 6][c] = p;
        }
        __syncthreads();
    }

    const float ec = __expf(sc);
    Wn += ec;
    En += ec * word_emb[(size_t)iw * DIM + d];

    const float sptf = (float)spt_mask[t];
    const float nrmf = (1.f - sptf) * masks[t];

    float eo;
    if (sptf > 0.f)      eo = Es / Ws;
    else if (nrmf > 0.f) eo = En / Wn;
    else                 eo = word_emb[(size_t)iw * DIM + d];
    out[(size_t)t * DIM + d] = eo;

    if (d == 0) {
        float bnv = cv[0]; int bni = ci[0];
        if (needN) {
            bnv = -INFINITY; bni = 0;
            #pragma unroll
            for (int c = 0; c < 3; ++c) {
                if (cv[c] > -1e30f) {
                    const float s = (float)(sredN[0][c] + sredN[1][c])
                                  + b_nrm[ci[c]]
                                  + g_nrm[(size_t)t * (NWRDC + 1) + ci[c]];
                    if (s > bnv || (s == bnv && ci[c] < bni)) { bnv = s; bni = ci[c]; }
                }
            }
        }
        float bsv = dv[0]; int bsi = di[0];
        if (needS) {
            bsv = -INFINITY; bsi = 0;
            #pragma unroll
            for (int c = 0; c < 3; ++c) {
                if (dv[c] > -1e30f) {
                    const float s = (float)(sredS[0][c] + sredS[1][c])
                                  + b_spt[di[c]]
                                  + g_spt[(size_t)t * NTGTC + di[c]];
                    if (s > bsv || (s == bsv && di[c] < bsi)) { bsv = s; bsi = di[c]; }
                }
            }
        }
        const int ynrm = (sc > bnv) ? iw : bni;
        const int yspt = tgt_ids[bsi];
        int obf;
        if (sptf > 0.f)      obf = yspt;
        else if (nrmf > 0.f) obf = ynrm;
        else                 obf = iw;
        out[(size_t)TOK * DIM + t]       = (float)obf;
        out[(size_t)TOK * DIM + TOK + t] = sptf;
    }
}

// ---------------------------------------------------------------------------
extern "C" void kernel_launch(void* const* d_in, const int* in_sizes, int n_in,
                              void* d_out, int out_size, void* d_ws, size_t ws_size,
                              hipStream_t stream)
{
    const int*   inp_word = (const int*)d_in[0];
    const float* masks    = (const float*)d_in[1];
    const int*   spt_mask = (const int*)d_in[2];
    const int*   tgt_ids  = (const int*)d_in[3];
    const float* ctx      = (const float*)d_in[4];
    const float* W_spt    = (const float*)d_in[5];
    const float* b_spt    = (const float*)d_in[6];
    const float* W_nrm    = (const float*)d_in[7];
    const float* b_nrm    = (const float*)d_in[8];
    const float* W_cpy    = (const float*)d_in[9];
    const float* b_cpy    = (const float*)d_in[10];
    const float* word_emb = (const float*)d_in[11];
    const float* word_emb_tgt = (const float*)d_in[12];
    const float* g_spt    = (const float*)d_in[13];
    const float* g_nrm    = (const float*)d_in[14];
    float* out = (float*)d_out;

    char* wsb = (char*)d_ws;
    // layout (bytes):
    //   pcpyP   @ 0          (32768)
    //   ctxh    @ 32768      (2 MB)  ctxm @ 2129920  ctxl @ 4227072
    //   Wt_nrm  @ 6324224    (65,536,000)  -> 71,860,224
    //   Wt_spt  @ 71860224   (4,194,304; 2048 padded rows) -> 76,054,528
    //   stats   @ 76054528   ((NVn+NVs) * 552,960)
    float*  pcpyP = (float*)wsb;
    ushort* ctxh  = (ushort*)(wsb + 32768);
    ushort* ctxm  = ctxh + 1048576;
    ushort* ctxl  = ctxm + 1048576;
    ushort* WtN   = (ushort*)(wsb + 6324224);
    ushort* WtS   = (ushort*)(wsb + 71860224);
    char*   region = wsb + 76054528;
    const size_t base = 76054528;
    const size_t per_split = (size_t)TOK * (1 + 3 + 3 + DIM) * 4;   // 552960

    int NVn = 1, NVs = 1;
    {
        const int tn[8] = {64, 48, 32, 16, 8, 4, 2, 1};
        const int ts[8] = { 8,  8,  8,  8, 8, 4, 2, 1};
        for (int pi = 0; pi < 8; ++pi) {
            const size_t need = base + (size_t)(tn[pi] + ts[pi]) * per_split;
            if (ws_size >= need) { NVn = tn[pi]; NVs = ts[pi]; break; }
        }
    }

    float* nW  = (float*)region;
    float* nBV = nW + (size_t)NVn * TOK;
    int*   nBI = (int*)(nBV + (size_t)NVn * TOK * 3);
    float* nE  = (float*)(nBI + (size_t)NVn * TOK * 3);
    float* sW  = nE + (size_t)NVn * TOK * DIM;
    float* sBV = sW + (size_t)NVs * TOK;
    int*   sBI = (int*)(sBV + (size_t)NVs * TOK * 3);
    float* sE  = (float*)(sBI + (size_t)NVs * TOK * 3);

    const int tps_n = (250 + NVn - 1) / NVn;
    const int tps_s = (16 + NVs - 1) / NVs;

    split_ctx3<<<dim3(TOK * HSZ / 1024), dim3(256), 0, stream>>>(ctx, ctxh, ctxm, ctxl);
    conv_wt<<<dim3(125, 8), dim3(256), 0, stream>>>(W_nrm, NWRDC, WtN);
    conv_wt<<<dim3(8, 8), dim3(256), 0, stream>>>(W_spt, NTGTC, WtS);
    cpy_fused<<<dim3(64), dim3(256), 0, stream>>>(ctxh, ctxm, ctxl, W_cpy, ctx, b_cpy, pcpyP);
    head_pre<<<dim3(NVn, 8), dim3(256), 0, stream>>>(
        ctxh, WtN, b_nrm, g_nrm, word_emb, NWRDC, NWRDC + 1,
        tps_n, 250, nW, nBV, nBI, nE);
    head_pre<<<dim3(NVs, 8), dim3(256), 0, stream>>>(
        ctxh, WtS, b_spt, g_spt, word_emb_tgt, NTGTC, NTGTC,
        tps_s, 16, sW, sBV, sBI, sE);
    combine2<<<dim3(TOK), dim3(128), 0, stream>>>(
        inp_word, masks, spt_mask, tgt_ids, word_emb, pcpyP, g_nrm, g_spt, ctx,
        b_nrm, b_spt, W_nrm, W_spt,
        nW, nBV, nBI, nE, NVn, sW, sBV, sBI, sE, NVs, out);
    (void)in_sizes; (void)n_in; (void)out_size;
}